// Round 1
// baseline (377.623 us; speedup 1.0000x reference)
//
#include <hip/hip_runtime.h>
#include <hip/hip_bf16.h>
#include <math.h>

#define BATH 512
#define NH 8
#define HS 128
#define EMB 1024
#define NE 64
#define ES 128

// ---------------- GEMM: C[M,N] = A[M,K] @ B[N,K]^T (all row-major f32) ---------------
#define BM 64
#define BN 64
#define BKK 32

__global__ __launch_bounds__(256) void gemm_nt(const float* __restrict__ A,
                                               const float* __restrict__ B,
                                               float* __restrict__ C,
                                               int M, int N, int K)
{
    __shared__ float As[BKK][BM + 4];
    __shared__ float Bs[BKK][BN + 4];
    const int bm = blockIdx.y * BM;
    const int bn = blockIdx.x * BN;
    const int tid = threadIdx.x;
    const int tx = tid & 15;   // n-dim
    const int ty = tid >> 4;   // m-dim
    float acc[4][4] = {};

    for (int k0 = 0; k0 < K; k0 += BKK) {
#pragma unroll
        for (int i = 0; i < 2; ++i) {
            int s = tid + i * 256;            // 0..511 slots, 8 float4 per row
            int m = s >> 3, k4 = s & 7;
            const float4 v = *(const float4*)(A + (size_t)(bm + m) * K + k0 + k4 * 4);
            As[k4 * 4 + 0][m] = v.x; As[k4 * 4 + 1][m] = v.y;
            As[k4 * 4 + 2][m] = v.z; As[k4 * 4 + 3][m] = v.w;
        }
#pragma unroll
        for (int i = 0; i < 2; ++i) {
            int s = tid + i * 256;
            int n = s >> 3, k4 = s & 7;
            const float4 v = *(const float4*)(B + (size_t)(bn + n) * K + k0 + k4 * 4);
            Bs[k4 * 4 + 0][n] = v.x; Bs[k4 * 4 + 1][n] = v.y;
            Bs[k4 * 4 + 2][n] = v.z; Bs[k4 * 4 + 3][n] = v.w;
        }
        __syncthreads();
#pragma unroll
        for (int kk = 0; kk < BKK; ++kk) {
            const float4 a = *(const float4*)&As[kk][ty * 4];
            const float4 b = *(const float4*)&Bs[kk][tx * 4];
            const float av[4] = {a.x, a.y, a.z, a.w};
            const float bv[4] = {b.x, b.y, b.z, b.w};
#pragma unroll
            for (int jm = 0; jm < 4; ++jm)
#pragma unroll
                for (int jn = 0; jn < 4; ++jn)
                    acc[jm][jn] += av[jm] * bv[jn];
        }
        __syncthreads();
    }
#pragma unroll
    for (int jm = 0; jm < 4; ++jm)
#pragma unroll
        for (int jn = 0; jn < 4; ++jn)
            C[(size_t)(bm + ty * 4 + jm) * N + bn + tx * 4 + jn] = acc[jm][jn];
}

// ---------------- V column-sum per expert tile: vsum[he][d] = sum_s V[he][s][d] -----
__global__ __launch_bounds__(128) void vsum_kernel(const float* __restrict__ v_ffwd,
                                                   float* __restrict__ vsum)
{
    const int he = blockIdx.x;        // h*NE + e
    const int d  = threadIdx.x;       // 0..127
    const float* vp = v_ffwd + (size_t)he * (ES * HS);
    float s = 0.f;
    for (int sl = 0; sl < ES; ++sl) s += vp[(size_t)sl * HS + d];
    vsum[he * HS + d] = s;
}

// ---------------- router: scores + biased top-2 + softmax gate + expert counts -------
__global__ __launch_bounds__(64) void router_topk(
    const float* __restrict__ q2, const float* __restrict__ router,
    const float* __restrict__ bias, int* __restrict__ idx,
    float* __restrict__ gate, int* __restrict__ counts)
{
    const int blk = blockIdx.x;            // h*BATH + b
    const int h = blk >> 9;
    const int b = blk & (BATH - 1);
    const int e = threadIdx.x;             // 0..63 == lane == expert
    const float* qp = q2 + (size_t)b * EMB + h * HS;
    const float* rp = router + (size_t)h * HS * NE + e;
    float s = 0.f;
#pragma unroll 8
    for (int d = 0; d < HS; ++d) s += qp[d] * rp[(size_t)d * NE];
    const float biased = s + bias[h * NE + e];

    // top-1 (tie -> lower index, matching lax.top_k stability)
    float v = biased; int vi = e;
#pragma unroll
    for (int off = 32; off > 0; off >>= 1) {
        float v2 = __shfl_xor(v, off);
        int   i2 = __shfl_xor(vi, off);
        if (v2 > v || (v2 == v && i2 < vi)) { v = v2; vi = i2; }
    }
    const int e1 = vi;
    // top-2
    float w = (e == e1) ? -3.4e38f : biased; int wi = e;
#pragma unroll
    for (int off = 32; off > 0; off >>= 1) {
        float v2 = __shfl_xor(w, off);
        int   i2 = __shfl_xor(wi, off);
        if (v2 > w || (v2 == w && i2 < wi)) { w = v2; wi = i2; }
    }
    const int e2 = wi;
    const float raw1 = __shfl(s, e1);
    const float raw2 = __shfl(s, e2);
    if (e == 0) {
        const float g1 = 1.f / (1.f + expf(raw2 - raw1));  // softmax over {raw1, raw2}
        idx[blk * 2 + 0]  = e1;
        idx[blk * 2 + 1]  = e2;
        gate[blk * 2 + 0] = g1;
        gate[blk * 2 + 1] = 1.f - g1;
        atomicAdd(&counts[h * NE + e1], 1);
        atomicAdd(&counts[h * NE + e2], 1);
    }
}

// ---------------- exclusive prefix over 512 expert counts; zero cursors --------------
__global__ __launch_bounds__(512) void scan_offsets(const int* __restrict__ counts,
                                                    int* __restrict__ offs,
                                                    int* __restrict__ cursor)
{
    __shared__ int tmp[512];
    const int t = threadIdx.x;
    const int c = counts[t];
    tmp[t] = c;
    __syncthreads();
    for (int off = 1; off < 512; off <<= 1) {
        int add = (t >= off) ? tmp[t - off] : 0;
        __syncthreads();
        tmp[t] += add;
        __syncthreads();
    }
    offs[t]   = tmp[t] - c;   // exclusive
    cursor[t] = 0;
}

// ---------------- scatter selection records into per-expert contiguous lists ---------
__global__ __launch_bounds__(256) void scatter_tokens(const int* __restrict__ idx,
                                                      const int* __restrict__ offs,
                                                      int* __restrict__ cursor,
                                                      int* __restrict__ list)
{
    const int g = blockIdx.x * blockDim.x + threadIdx.x;   // h*BATH + b
    if (g >= NH * BATH) return;
    const int h = g >> 9;
#pragma unroll
    for (int k = 0; k < 2; ++k) {
        const int e = idx[g * 2 + k];
        const int p = atomicAdd(&cursor[h * NE + e], 1);
        list[offs[h * NE + e] + p] = ((g & (BATH - 1)) << 1) | k;
    }
}

// ---------------- expert-major block-sparse attention ---------------------------------
// block = one (h,e) expert tile; K-row kept in registers; 16-token chunks via LDS.
__global__ __launch_bounds__(128) void expert_attn(
    const float* __restrict__ q2, const float* __restrict__ k_ffwd,
    const float* __restrict__ v_ffwd, const float* __restrict__ vsum,
    const float* __restrict__ gate, const int* __restrict__ list,
    const int* __restrict__ counts, const int* __restrict__ offs,
    float* __restrict__ agg2)
{
    const int he = blockIdx.x;             // h*NE + e
    const int h  = he >> 6;
    const int n  = counts[he];
    if (n == 0) return;
    const int base = offs[he];
    const int t = threadIdx.x;             // 0..127 (slot in phase A, dim in phase B)

    __shared__ float qs[16][128];
    __shared__ float ls2[16][128];
    __shared__ int   tok[16];

    const float* Kp = k_ffwd + (size_t)he * (ES * HS);
    const float* Vp = v_ffwd + (size_t)he * (ES * HS);
    const float  myvs = vsum[he * HS + t];

    // K row for slot t -> 32 float4 in registers (reused across all chunks)
    float4 kr[32];
#pragma unroll
    for (int j = 0; j < 32; ++j)
        kr[j] = *(const float4*)(Kp + (size_t)t * HS + j * 4);

    for (int c0 = 0; c0 < n; c0 += 16) {
        const int cnt = min(16, n - c0);
        if (t < 16) tok[t] = (t < cnt) ? list[base + c0 + t] : 0;
        __syncthreads();
#pragma unroll
        for (int i = 0; i < 16; ++i) {
            const int bb = tok[i] >> 1;
            qs[i][t] = (i < cnt) ? q2[(size_t)bb * EMB + h * HS + t] : 0.f;
        }
        __syncthreads();
        // phase A: logits for slot t over chunk tokens, exp
        float lg[16];
#pragma unroll
        for (int i = 0; i < 16; ++i) {
            float acc = 0.f;
#pragma unroll
            for (int j = 0; j < 32; ++j) {
                const float4 qv = *(const float4*)&qs[i][j * 4];
                acc += kr[j].x * qv.x + kr[j].y * qv.y + kr[j].z * qv.z + kr[j].w * qv.w;
            }
            lg[i] = expf(acc);
        }
#pragma unroll
        for (int i = 0; i < 16; ++i) ls2[i][t] = lg[i];  // conflict-free (contiguous t)
        __syncthreads();
        // phase B: o[i][d=t] = sum_s exp(l)[i][s] * V[s][d]
        float oacc[16];
#pragma unroll
        for (int i = 0; i < 16; ++i) oacc[i] = 0.f;
        for (int s = 0; s < 128; ++s) {
            const float vval = Vp[(size_t)s * HS + t];   // coalesced across t
#pragma unroll
            for (int i = 0; i < 16; ++i) oacc[i] += ls2[i][s] * vval;  // broadcast reads
        }
#pragma unroll
        for (int i = 0; i < 16; ++i) {
            if (i < cnt) {
                const int bb = tok[i] >> 1;
                const int kk = tok[i] & 1;
                const float g = gate[(((h << 9) | bb) << 1) + kk];
                atomicAdd(&agg2[(size_t)bb * EMB + h * HS + t], g * (oacc[i] - myvs));
            }
        }
        __syncthreads();
    }
}

extern "C" void kernel_launch(void* const* d_in, const int* in_sizes, int n_in,
                              void* d_out, int out_size, void* d_ws, size_t ws_size,
                              hipStream_t stream)
{
    const float* x      = (const float*)d_in[0];
    const float* w_mh   = (const float*)d_in[1];
    const float* w_mg   = (const float*)d_in[2];
    const float* router = (const float*)d_in[3];
    const float* k_ffwd = (const float*)d_in[4];
    const float* v_ffwd = (const float*)d_in[5];
    const float* bias   = (const float*)d_in[6];
    float* out = (float*)d_out;

    char* ws = (char*)d_ws;
    float* q2     = (float*)(ws);                 // [512][1024]  q in [b][h*128+d]
    float* agg2   = (float*)(ws + 2097152);       // [512][1024]  gated aggregate
    float* vsum   = (float*)(ws + 4194304);       // [512][128]   per-(h,e) V col-sum
    float* gate   = (float*)(ws + 4456448);       // [4096][2]
    int*   idx    = (int*)  (ws + 4489216);       // [4096][2]
    int*   counts = (int*)  (ws + 4521984);       // [512]
    int*   offs   = (int*)  (ws + 4524032);       // [512]
    int*   cursor = (int*)  (ws + 4526080);       // [512]
    int*   list   = (int*)  (ws + 4528128);       // [8192]

    hipMemsetAsync(agg2, 0, 2097152, stream);
    hipMemsetAsync(counts, 0, 2048, stream);

    // q = x @ w_mh^T  -> q2[b][h*128+d]
    gemm_nt<<<dim3(16, 8), 256, 0, stream>>>(x, w_mh, q2, BATH, EMB, EMB);
    vsum_kernel<<<dim3(NH * NE), 128, 0, stream>>>(v_ffwd, vsum);
    router_topk<<<dim3(NH * BATH), 64, 0, stream>>>(q2, router, bias, idx, gate, counts);
    scan_offsets<<<dim3(1), 512, 0, stream>>>(counts, offs, cursor);
    scatter_tokens<<<dim3(16), 256, 0, stream>>>(idx, offs, cursor, list);
    expert_attn<<<dim3(NH * NE), 128, 0, stream>>>(q2, k_ffwd, v_ffwd, vsum,
                                                   gate, list, counts, offs, agg2);
    // y = agg2 @ w_mg^T
    gemm_nt<<<dim3(16, 8), 256, 0, stream>>>(agg2, w_mg, out, BATH, EMB, EMB);
}

// Round 4
// 214.181 us; speedup vs baseline: 1.7631x; 1.7631x over previous
//
#include <hip/hip_runtime.h>
#include <hip/hip_bf16.h>
#include <math.h>

#define BATH 512
#define NH 8
#define HS 128
#define EMB 1024
#define NE 64
#define ES 128

// ---------------- GEMM with split-K: Cslab[z] = A[:, zK..] @ B[:, zK..]^T ------------
#define BM 64
#define BN 64
#define BKK 32

__global__ __launch_bounds__(256) void gemm_nt_ks(const float* __restrict__ A,
                                                  const float* __restrict__ B,
                                                  float* __restrict__ Cslab,
                                                  int M, int N, int K)
{
    const int kslice = K / gridDim.z;
    const int kbeg = blockIdx.z * kslice;
    const int bm = blockIdx.y * BM;
    const int bn = blockIdx.x * BN;
    const int tid = threadIdx.x;
    const int tx = tid & 15;   // n-dim
    const int ty = tid >> 4;   // m-dim
    float* C = Cslab + (size_t)blockIdx.z * M * N;

    __shared__ float As[BKK][BM + 4];
    __shared__ float Bs[BKK][BN + 4];
    float acc[4][4] = {};

    for (int k0 = kbeg; k0 < kbeg + kslice; k0 += BKK) {
#pragma unroll
        for (int i = 0; i < 2; ++i) {
            int s = tid + i * 256;            // 512 slots: 64 rows x 8 float4
            int m = s >> 3, k4 = s & 7;
            const float4 v = *(const float4*)(A + (size_t)(bm + m) * K + k0 + k4 * 4);
            As[k4 * 4 + 0][m] = v.x; As[k4 * 4 + 1][m] = v.y;
            As[k4 * 4 + 2][m] = v.z; As[k4 * 4 + 3][m] = v.w;
        }
#pragma unroll
        for (int i = 0; i < 2; ++i) {
            int s = tid + i * 256;
            int n = s >> 3, k4 = s & 7;
            const float4 v = *(const float4*)(B + (size_t)(bn + n) * K + k0 + k4 * 4);
            Bs[k4 * 4 + 0][n] = v.x; Bs[k4 * 4 + 1][n] = v.y;
            Bs[k4 * 4 + 2][n] = v.z; Bs[k4 * 4 + 3][n] = v.w;
        }
        __syncthreads();
#pragma unroll
        for (int kk = 0; kk < BKK; ++kk) {
            const float4 a = *(const float4*)&As[kk][ty * 4];
            const float4 b = *(const float4*)&Bs[kk][tx * 4];
            const float av[4] = {a.x, a.y, a.z, a.w};
            const float bv[4] = {b.x, b.y, b.z, b.w};
#pragma unroll
            for (int jm = 0; jm < 4; ++jm)
#pragma unroll
                for (int jn = 0; jn < 4; ++jn)
                    acc[jm][jn] += av[jm] * bv[jn];
        }
        __syncthreads();
    }
#pragma unroll
    for (int jm = 0; jm < 4; ++jm)
#pragma unroll
        for (int jn = 0; jn < 4; ++jn)
            C[(size_t)(bm + ty * 4 + jm) * N + bn + tx * 4 + jn] = acc[jm][jn];
}

// ---------------- sum 4 split-K slabs -> dst (float4 per thread) ---------------------
__global__ __launch_bounds__(256) void reduce4(const float* __restrict__ slab,
                                               float* __restrict__ dst)
{
    const size_t i = (size_t)blockIdx.x * 256 + threadIdx.x;   // float4 index
    const float4* s0 = (const float4*)slab;
    const size_t stride = (size_t)BATH * EMB / 4;              // 131072 float4
    float4 a = s0[i], b = s0[i + stride], c = s0[i + 2 * stride], d = s0[i + 3 * stride];
    float4 r;
    r.x = a.x + b.x + c.x + d.x;
    r.y = a.y + b.y + c.y + d.y;
    r.z = a.z + b.z + c.z + d.z;
    r.w = a.w + b.w + c.w + d.w;
    ((float4*)dst)[i] = r;
}

// ---------------- router: scores + biased top-2 + softmax gate + expert counts -------
__global__ __launch_bounds__(64) void router_topk(
    const float* __restrict__ q2, const float* __restrict__ router,
    const float* __restrict__ bias, int* __restrict__ idx,
    float* __restrict__ gate, int* __restrict__ counts)
{
    const int blk = blockIdx.x;            // h*BATH + b
    const int h = blk >> 9;
    const int b = blk & (BATH - 1);
    const int e = threadIdx.x;             // 0..63 == lane == expert
    const float* qp = q2 + (size_t)b * EMB + h * HS;
    const float* rp = router + (size_t)h * HS * NE + e;
    float s = 0.f;
#pragma unroll 8
    for (int d = 0; d < HS; ++d) s += qp[d] * rp[(size_t)d * NE];
    const float biased = s + bias[h * NE + e];

    float v = biased; int vi = e;
#pragma unroll
    for (int off = 32; off > 0; off >>= 1) {
        float v2 = __shfl_xor(v, off);
        int   i2 = __shfl_xor(vi, off);
        if (v2 > v || (v2 == v && i2 < vi)) { v = v2; vi = i2; }
    }
    const int e1 = vi;
    float w = (e == e1) ? -3.4e38f : biased; int wi = e;
#pragma unroll
    for (int off = 32; off > 0; off >>= 1) {
        float v2 = __shfl_xor(w, off);
        int   i2 = __shfl_xor(wi, off);
        if (v2 > w || (v2 == w && i2 < wi)) { w = v2; wi = i2; }
    }
    const int e2 = wi;
    const float raw1 = __shfl(s, e1);
    const float raw2 = __shfl(s, e2);
    if (e == 0) {
        const float g1 = 1.f / (1.f + expf(raw2 - raw1));
        idx[blk * 2 + 0]  = e1;
        idx[blk * 2 + 1]  = e2;
        gate[blk * 2 + 0] = g1;
        gate[blk * 2 + 1] = 1.f - g1;
        atomicAdd(&counts[h * NE + e1], 1);
        atomicAdd(&counts[h * NE + e2], 1);
    }
}

// ---- exclusive scan over 512 counts; zero cursors; build 16-token chunk worklist ----
__global__ __launch_bounds__(512) void scan_offsets(const int* __restrict__ counts,
                                                    int* __restrict__ offs,
                                                    int* __restrict__ cursor,
                                                    int* __restrict__ chunks,
                                                    int* __restrict__ nchunks)
{
    __shared__ int tmp[512];
    const int t = threadIdx.x;
    const int c = counts[t];
    tmp[t] = c;
    __syncthreads();
    for (int off = 1; off < 512; off <<= 1) {
        int add = (t >= off) ? tmp[t - off] : 0;
        __syncthreads();
        tmp[t] += add;
        __syncthreads();
    }
    offs[t]   = tmp[t] - c;
    cursor[t] = 0;
    const int nch = (c + 15) >> 4;
    __syncthreads();
    tmp[t] = nch;
    __syncthreads();
    for (int off = 1; off < 512; off <<= 1) {
        int add = (t >= off) ? tmp[t - off] : 0;
        __syncthreads();
        tmp[t] += add;
        __syncthreads();
    }
    const int chbase = tmp[t] - nch;
    for (int j = 0; j < nch; ++j) chunks[chbase + j] = (t << 6) | j;
    if (t == 511) *nchunks = tmp[511];
}

// ---------------- scatter selection records into per-expert contiguous lists ---------
__global__ __launch_bounds__(256) void scatter_tokens(const int* __restrict__ idx,
                                                      const int* __restrict__ offs,
                                                      int* __restrict__ cursor,
                                                      int* __restrict__ list)
{
    const int g = blockIdx.x * blockDim.x + threadIdx.x;   // h*BATH + b
    if (g >= NH * BATH) return;
    const int h = g >> 9;
#pragma unroll
    for (int k = 0; k < 2; ++k) {
        const int e = idx[g * 2 + k];
        const int p = atomicAdd(&cursor[h * NE + e], 1);
        list[offs[h * NE + e] + p] = ((g & (BATH - 1)) << 1) | k;
    }
}

// ---------------- expert-major block-sparse attention, one block per 16-token chunk --
__global__ __launch_bounds__(128) void expert_attn(
    const float* __restrict__ q2, const float* __restrict__ k_ffwd,
    const float* __restrict__ v_ffwd, const float* __restrict__ gate,
    const int* __restrict__ list, const int* __restrict__ counts,
    const int* __restrict__ offs, const int* __restrict__ chunks,
    const int* __restrict__ nchunks, float* __restrict__ agg2)
{
    if ((int)blockIdx.x >= *nchunks) return;
    const int rec = chunks[blockIdx.x];
    const int he = rec >> 6;
    const int cidx = rec & 63;
    const int h  = he >> 6;
    const int n  = counts[he];
    const int base = offs[he];
    const int c0 = cidx << 4;
    const int cnt = min(16, n - c0);
    const int t = threadIdx.x;             // slot (phase A) / dim (phase B)

    __shared__ float qs[16][128];
    __shared__ float ls2[16][128];
    __shared__ int   tok[16];

    const float* Kp = k_ffwd + (size_t)he * (ES * HS);
    const float* Vp = v_ffwd + (size_t)he * (ES * HS);

    if (t < 16) tok[t] = (t < cnt) ? list[base + c0 + t] : 0;
    __syncthreads();
#pragma unroll
    for (int i = 0; i < 16; ++i) {
        const int bb = tok[i] >> 1;
        qs[i][t] = (i < cnt) ? q2[(size_t)bb * EMB + h * HS + t] : 0.f;
    }
    __syncthreads();

    // phase A: logits for K-slot t over the 16 chunk tokens, 4 K-column passes
    float lg[16] = {};
#pragma unroll
    for (int j0 = 0; j0 < 4; ++j0) {
        float4 kr8[8];
#pragma unroll
        for (int j = 0; j < 8; ++j)
            kr8[j] = *(const float4*)(Kp + (size_t)t * HS + j0 * 32 + j * 4);
#pragma unroll
        for (int i = 0; i < 16; ++i) {
            float a = 0.f;
#pragma unroll
            for (int j = 0; j < 8; ++j) {
                const float4 qv = *(const float4*)&qs[i][j0 * 32 + j * 4];
                a += kr8[j].x * qv.x + kr8[j].y * qv.y + kr8[j].z * qv.z + kr8[j].w * qv.w;
            }
            lg[i] += a;
        }
    }
#pragma unroll
    for (int i = 0; i < 16; ++i) ls2[i][t] = expf(lg[i]);
    __syncthreads();

    // phase B: o[i][d=t] = sum_s exp(l)[i][s] * V[s][d]; also fold in vsum
    float oacc[16] = {};
    float vs = 0.f;
#pragma unroll 2
    for (int s0 = 0; s0 < 128; s0 += 8) {
        float vv[8];
#pragma unroll
        for (int u = 0; u < 8; ++u) vv[u] = Vp[(size_t)(s0 + u) * HS + t];
#pragma unroll
        for (int u = 0; u < 8; ++u) {
            vs += vv[u];
#pragma unroll
            for (int i = 0; i < 16; ++i) oacc[i] += ls2[i][s0 + u] * vv[u];
        }
    }
#pragma unroll
    for (int i = 0; i < 16; ++i) {
        if (i < cnt) {
            const int bb = tok[i] >> 1;
            const int kk = tok[i] & 1;
            const float g = gate[(((h << 9) | bb) << 1) + kk];
            atomicAdd(&agg2[(size_t)bb * EMB + h * HS + t], g * (oacc[i] - vs));
        }
    }
}

extern "C" void kernel_launch(void* const* d_in, const int* in_sizes, int n_in,
                              void* d_out, int out_size, void* d_ws, size_t ws_size,
                              hipStream_t stream)
{
    const float* x      = (const float*)d_in[0];
    const float* w_mh   = (const float*)d_in[1];
    const float* w_mg   = (const float*)d_in[2];
    const float* router = (const float*)d_in[3];
    const float* k_ffwd = (const float*)d_in[4];
    const float* v_ffwd = (const float*)d_in[5];
    const float* bias   = (const float*)d_in[6];
    float* out = (float*)d_out;

    char* ws = (char*)d_ws;
    float* q2      = (float*)(ws);                  // [512][1024]
    float* agg2    = (float*)(ws + 2097152);        // [512][1024]
    float* slab    = (float*)(ws + 4194304);        // 4 x [512][1024] split-K slabs
    float* gate    = (float*)(ws + 12582912);       // [4096][2]
    int*   idx     = (int*)  (ws + 12615680);       // [4096][2]
    int*   counts  = (int*)  (ws + 12648448);       // [512]
    int*   offs    = (int*)  (ws + 12650496);       // [512]
    int*   cursor  = (int*)  (ws + 12652544);       // [512]
    int*   list    = (int*)  (ws + 12654592);       // [8192]
    int*   chunks  = (int*)  (ws + 12687360);       // [1024]
    int*   nchunks = (int*)  (ws + 12691456);       // [1]

    hipMemsetAsync(agg2, 0, 2097152, stream);
    hipMemsetAsync(counts, 0, 2048, stream);

    gemm_nt_ks<<<dim3(16, 8, 4), 256, 0, stream>>>(x, w_mh, slab, BATH, EMB, EMB);
    reduce4<<<512, 256, 0, stream>>>(slab, q2);
    router_topk<<<dim3(NH * BATH), 64, 0, stream>>>(q2, router, bias, idx, gate, counts);
    scan_offsets<<<1, 512, 0, stream>>>(counts, offs, cursor, chunks, nchunks);
    scatter_tokens<<<16, 256, 0, stream>>>(idx, offs, cursor, list);
    expert_attn<<<1024, 128, 0, stream>>>(q2, k_ffwd, v_ffwd, gate, list,
                                          counts, offs, chunks, nchunks, agg2);
    gemm_nt_ks<<<dim3(16, 8, 4), 256, 0, stream>>>(agg2, w_mg, slab, BATH, EMB, EMB);
    reduce4<<<512, 256, 0, stream>>>(slab, out);
}